// Round 13
// baseline (80.084 us; speedup 1.0000x reference)
//
#include <hip/hip_runtime.h>
#include <hip/hip_bf16.h>
#include <stdint.h>

typedef short bf16x8 __attribute__((ext_vector_type(8)));
typedef float f32x4 __attribute__((ext_vector_type(4)));

#define D  512
#define NB 4096
#define NT 8192

__device__ __forceinline__ unsigned short f2bf(float f) {
    __hip_bfloat16 h = __float2bfloat16(f);
    return *reinterpret_cast<unsigned short*>(&h);
}

// Fused fp32->bf16 convert + row squared-norm for BOTH inputs; x rows also
// write the fp32 passthrough (output 0). One wave per row. HBM-floor bound.
__global__ __launch_bounds__(256) void prep_kernel(
    const float* __restrict__ x, const float* __restrict__ y,
    unsigned short* __restrict__ xb, unsigned short* __restrict__ yb,
    float* __restrict__ x2, float* __restrict__ y2, float* __restrict__ copy)
{
    const int grow = blockIdx.x * 4 + (threadIdx.x >> 6);
    const int lane = threadIdx.x & 63;
    const bool isX = grow < NB;
    const int row  = isX ? grow : grow - NB;
    const float* src = isX ? x : y;
    unsigned short* dst = isX ? xb : yb;
    float* norms = isX ? x2 : y2;

    const float4* rp = reinterpret_cast<const float4*>(src + (size_t)row * D);
    float4 v0 = rp[lane * 2];
    float4 v1 = rp[lane * 2 + 1];
    if (isX) {
        float4* cp = reinterpret_cast<float4*>(copy + (size_t)row * D);
        cp[lane * 2]     = v0;
        cp[lane * 2 + 1] = v1;
    }
    float s = v0.x*v0.x + v0.y*v0.y + v0.z*v0.z + v0.w*v0.w
            + v1.x*v1.x + v1.y*v1.y + v1.z*v1.z + v1.w*v1.w;
    union { unsigned short h[8]; int4 v; } u;
    u.h[0] = f2bf(v0.x); u.h[1] = f2bf(v0.y); u.h[2] = f2bf(v0.z); u.h[3] = f2bf(v0.w);
    u.h[4] = f2bf(v1.x); u.h[5] = f2bf(v1.y); u.h[6] = f2bf(v1.z); u.h[7] = f2bf(v1.w);
    reinterpret_cast<int4*>(dst + (size_t)row * D)[lane] = u.v;
    #pragma unroll
    for (int off = 32; off > 0; off >>= 1) s += __shfl_xor(s, off);
    if (lane == 0) norms[row] = s;
}

// Load/compute wave-specialized GEMM (dual of R12): 512 blocks (2/CU),
// 6 waves = 4 compute (R10 engine: 128x256 tile, wave-tile 128x64, 12
// ds_read + 32 MFMA per g) + 2 load waves (all global_load_lds + all vmcnt
// checkpoints; 12 insts/g; 3 rotating bufs, stage g+2, vmcnt(12)).
// Each block: 2 col-adjacent tiles = unified g=0..31 pipeline (A-panel kt
// re-read from L2 for tile 1). Compute waves NEVER wait vmcnt: their FIFO
// holds only the boundary's 32 fp32 stores, which drain in the background
// under the next tile's 16-kt loop (no forced drains possible - the R3/R9
// failure is eliminated by construction). One shared barrier per g.
// LDS (ushort): buf b at b*12288: A 128x32 @+0, B 256x32 @+4096. 72 KiB.
__global__ __launch_bounds__(384) void gemm_sim_kernel(
    const unsigned short* __restrict__ X, const unsigned short* __restrict__ Y,
    const float* __restrict__ x2, const float* __restrict__ y2,
    float* __restrict__ out)
{
    __shared__ alignas(16) unsigned short lds[36864];   // 72 KiB

    const int t    = threadIdx.x;
    const int lane = t & 63;
    const int w    = t >> 6;                  // 0..5
    const bool isCompute = (w < 4);
    const int tl   = isCompute ? 0 : (t - 256);   // load-wave thread 0..127

    // 512 blocks: per XCD 32 rowTiles x 4 colPairs won't fit; use
    // 16 rowTiles x 4 colPairs per xcd-half (A 2MB + B 4MB streamed).
    const int bid = blockIdx.x;
    const int xcd = bid & 7;
    const int idx = bid >> 3;                           // 0..63
    const int rowBase  = ((xcd & 1) * 16 + (idx & 15)) * 128;
    const int colBase0 = ((xcd >> 1) * 4 + (idx >> 4)) * 512;   // 2 tiles

    // Load-wave staging (emulates R10's 256-thread map via T = tl + 128*i).
    // Chunk-XOR source swizzle (rule #21): identical for T and T+128.
    const int swz = ((tl & 3) ^ ((tl >> 3) & 3)) * 8;
    const unsigned short* gA = X + (size_t)(rowBase  + (tl >> 2)) * D + swz;
    const unsigned short* gB = Y + (size_t)(colBase0 + (tl >> 2)) * D + swz;

    // Compute-wave fragment constants (exact R10).
    const int cread = ((lane >> 4) ^ ((lane >> 1) & 3)) * 8;
    const int aoff = (lane & 15) * 32 + cread;
    const int boff = 4096 + (w * 64 + (lane & 15)) * 32 + cread;

    f32x4 acc[8][4] = {};

    // Norm preloads (compute waves; retired long before first use at g=15).
    float x2v[32], y2v[8];
    if (isCompute) {
        const int r0 = rowBase + ((lane >> 4) << 2);
        #pragma unroll
        for (int mi = 0; mi < 8; ++mi)
            #pragma unroll
            for (int q = 0; q < 4; ++q)
                x2v[mi * 4 + q] = x2[r0 + (mi >> 2) * 64 + (mi & 3) * 16 + q];
        #pragma unroll
        for (int tile = 0; tile < 2; ++tile)
            #pragma unroll
            for (int n = 0; n < 4; ++n)
                y2v[tile * 4 + n] = y2[colBase0 + tile * 256 + w * 64 + (lane & 15) + n * 16];
    }

#define BAR() do { asm volatile("" ::: "memory"); __builtin_amdgcn_s_barrier(); \
                   asm volatile("" ::: "memory"); } while (0)

#define GLD(SRC, DST) __builtin_amdgcn_global_load_lds( \
    (const __attribute__((address_space(1))) void*)(SRC), \
    (__attribute__((address_space(3))) void*)(DST), 16, 0, 0)

// Stage global step S (tile S>>4, kt S&15) into buf S%3. Load waves only.
#define STAGE(S) do { \
    _Pragma("unroll") \
    for (int i = 0; i < 2; ++i) { \
        _Pragma("unroll") \
        for (int L = 0; L < 2; ++L) \
            GLD(gA + (size_t)(32 * i + 64 * L) * D + ((S) & 15) * 32, \
                lds + ((S) % 3) * 12288 + tl * 8 + i * 1024 + L * 2048); \
        _Pragma("unroll") \
        for (int L = 0; L < 4; ++L) \
            GLD(gB + (size_t)(((S) >> 4) * 256 + 32 * i + 64 * L) * D + ((S) & 15) * 32, \
                lds + ((S) % 3) * 12288 + 4096 + tl * 8 + i * 1024 + L * 2048); \
    } \
} while (0)

// Boundary: transform acc -> sim, 32 direct fp32 stores (never waited).
#define BOUNDARY(TL) do { \
    const int col0 = colBase0 + (TL) * 256 + w * 64 + (lane & 15); \
    const int row0 = rowBase + ((lane >> 4) << 2); \
    _Pragma("unroll") \
    for (int mi = 0; mi < 8; ++mi) { \
        const int rbase = row0 + (mi >> 2) * 64 + (mi & 3) * 16; \
        _Pragma("unroll") \
        for (int q = 0; q < 4; ++q) { \
            float* orow = out + (size_t)(rbase + q) * NT; \
            _Pragma("unroll") \
            for (int n = 0; n < 4; ++n) { \
                float sq = fmaxf(x2v[mi * 4 + q] + y2v[(TL) * 4 + n] \
                                 - 2.0f * acc[mi][n][q], 0.0f); \
                orow[col0 + n * 16] = fminf(rsqrtf(sq), 1.0e6f); \
            } \
        } \
    } \
    _Pragma("unroll") \
    for (int mi = 0; mi < 8; ++mi) \
        _Pragma("unroll") \
        for (int n = 0; n < 4; ++n) \
            acc[mi][n] = (f32x4){0.f, 0.f, 0.f, 0.f}; \
} while (0)

#define GBODY(G) do { \
    if (isCompute) { \
        bf16x8 _a[2][4], _b[4]; \
        _Pragma("unroll") \
        for (int n = 0; n < 4; ++n) \
            _b[n] = *(const bf16x8*)(lds + ((G) % 3) * 12288 + boff + n * 512); \
        _Pragma("unroll") \
        for (int h = 0; h < 2; ++h) \
            _Pragma("unroll") \
            for (int m = 0; m < 4; ++m) \
                _a[h][m] = *(const bf16x8*)(lds + ((G) % 3) * 12288 + aoff + h * 2048 + m * 512); \
        __builtin_amdgcn_s_setprio(1); \
        _Pragma("unroll") \
        for (int h = 0; h < 2; ++h) \
            _Pragma("unroll") \
            for (int m = 0; m < 4; ++m) \
                _Pragma("unroll") \
                for (int n = 0; n < 4; ++n) \
                    acc[h * 4 + m][n] = __builtin_amdgcn_mfma_f32_16x16x32_bf16( \
                        _a[h][m], _b[n], acc[h * 4 + m][n], 0, 0, 0); \
        __builtin_amdgcn_s_setprio(0); \
        asm volatile("s_waitcnt lgkmcnt(0)" ::: "memory"); \
        __builtin_amdgcn_sched_barrier(0); \
        if (((G) & 15) == 15) BOUNDARY((G) >> 4); \
    } else { \
        if ((G) + 2 <= 31) STAGE((G) + 2); \
        if ((G) <= 29)      { asm volatile("s_waitcnt vmcnt(12)" ::: "memory"); } \
        else if ((G) == 30) { asm volatile("s_waitcnt vmcnt(0)"  ::: "memory"); } \
    } \
    if ((G) < 31) BAR(); \
} while (0)

    // Prologue: load waves stage g0,g1 (24 insts); vmcnt(12) -> g0 landed.
    if (!isCompute) {
        STAGE(0); STAGE(1);
        asm volatile("s_waitcnt vmcnt(12)" ::: "memory");
    }
    BAR();

#define G4(G)  GBODY(G); GBODY((G)+1); GBODY((G)+2); GBODY((G)+3);
    G4(0)  G4(4)  G4(8)  G4(12) G4(16) G4(20) G4(24) G4(28)
#undef G4
#undef GBODY
#undef BOUNDARY
#undef STAGE
#undef GLD
#undef BAR
}

extern "C" void kernel_launch(void* const* d_in, const int* in_sizes, int n_in,
                              void* d_out, int out_size, void* d_ws, size_t ws_size,
                              hipStream_t stream)
{
    const float* x = (const float*)d_in[0];
    const float* y = (const float*)d_in[1];
    float* out = (float*)d_out;
    char* ws = (char*)d_ws;

    unsigned short* xb = (unsigned short*)ws;                 // 4 MB
    unsigned short* yb = (unsigned short*)(ws + (4u << 20));  // 8 MB
    float* x2 = (float*)(ws + (12u << 20));                   // 16 KB
    float* y2 = (float*)(ws + (12u << 20) + 4 * NB);          // 32 KB

    prep_kernel<<<(NB + NT) / 4, 256, 0, stream>>>(x, y, xb, yb, x2, y2, out);
    gemm_sim_kernel<<<512, 384, 0, stream>>>(xb, yb, x2, y2, out + (size_t)NB * D);
}

// Round 14
// 78.703 us; speedup vs baseline: 1.0175x; 1.0175x over previous
//
#include <hip/hip_runtime.h>
#include <hip/hip_bf16.h>
#include <stdint.h>

typedef short bf16x8 __attribute__((ext_vector_type(8)));
typedef float f32x4 __attribute__((ext_vector_type(4)));

#define D  512
#define NB 4096
#define NT 8192

__device__ __forceinline__ unsigned short f2bf(float f) {
    __hip_bfloat16 h = __float2bfloat16(f);
    return *reinterpret_cast<unsigned short*>(&h);
}

// Fused fp32->bf16 convert + row squared-norm for BOTH inputs; x rows also
// write the fp32 passthrough (output 0). One wave per row. HBM-floor bound.
__global__ __launch_bounds__(256) void prep_kernel(
    const float* __restrict__ x, const float* __restrict__ y,
    unsigned short* __restrict__ xb, unsigned short* __restrict__ yb,
    float* __restrict__ x2, float* __restrict__ y2, float* __restrict__ copy)
{
    const int grow = blockIdx.x * 4 + (threadIdx.x >> 6);
    const int lane = threadIdx.x & 63;
    const bool isX = grow < NB;
    const int row  = isX ? grow : grow - NB;
    const float* src = isX ? x : y;
    unsigned short* dst = isX ? xb : yb;
    float* norms = isX ? x2 : y2;

    const float4* rp = reinterpret_cast<const float4*>(src + (size_t)row * D);
    float4 v0 = rp[lane * 2];
    float4 v1 = rp[lane * 2 + 1];
    if (isX) {
        float4* cp = reinterpret_cast<float4*>(copy + (size_t)row * D);
        cp[lane * 2]     = v0;
        cp[lane * 2 + 1] = v1;
    }
    float s = v0.x*v0.x + v0.y*v0.y + v0.z*v0.z + v0.w*v0.w
            + v1.x*v1.x + v1.y*v1.y + v1.z*v1.z + v1.w*v1.w;
    union { unsigned short h[8]; int4 v; } u;
    u.h[0] = f2bf(v0.x); u.h[1] = f2bf(v0.y); u.h[2] = f2bf(v0.z); u.h[3] = f2bf(v0.w);
    u.h[4] = f2bf(v1.x); u.h[5] = f2bf(v1.y); u.h[6] = f2bf(v1.z); u.h[7] = f2bf(v1.w);
    reinterpret_cast<int4*>(dst + (size_t)row * D)[lane] = u.v;
    #pragma unroll
    for (int off = 32; off > 0; off >>= 1) s += __shfl_xor(s, off);
    if (lane == 0) norms[row] = s;
}

// 128x256 tile, BK=32, 4 waves (1Mx4N, wave-tile 128x64), 3 rotating LDS
// buffers, merged single-phase K-tiles (R10 engine, 60.6 µs baseline).
// ONE change vs R10: epilogue sim stores are NON-TEMPORAL. Mechanism under
// test: 134 MB of normal stores stream through the 4 MB/XCD L2, evicting
// the staged A/B panels, so successor blocks' staging loads fall back to
// HBM exactly while HBM is write-saturated (why every "background burst"
// still stalled the next loop). nt keeps panels L2-resident and bypasses
// the write stream. Schedule, arithmetic, layout: byte-identical to R10.
// LDS (ushort): buf b at b*12288: A 128x32 @+0 (8 KB), B 256x32 @+4096
// (16 KB). 72 KiB total -> 2 blocks/CU co-resident.
__global__ __launch_bounds__(256, 2) void gemm_sim_kernel(
    const unsigned short* __restrict__ X, const unsigned short* __restrict__ Y,
    const float* __restrict__ x2, const float* __restrict__ y2,
    float* __restrict__ out)
{
    __shared__ alignas(16) unsigned short lds[36864];   // 72 KiB

    const int t    = threadIdx.x;
    const int lane = t & 63;
    const int w    = t >> 6;          // 0..3, wave col (64 cols each)

    // XCD swizzle, L2-fit: each XCD covers 16 rowTiles x 8 colTiles
    // (A 2 MB + B 2 MB = 4 MB = per-XCD L2).
    const int bid = blockIdx.x;
    const int xcd = bid & 7;
    const int idx = bid >> 3;                          // 0..127
    const int rowBase = ((xcd >> 2) * 16 + (idx & 15)) * 128;
    const int colBase = ((xcd & 3) * 8 + (idx >> 4)) * 256;

    // Staging: thread t writes 16 B chunks at LDS ushort off t*8 (+L*2048).
    // Chunk-XOR swizzle (rule #21): stored chunk c' holds global chunk
    // c' ^ ((row>>1)&3); folds to t-only constants for all L.
    const int swz = ((t & 3) ^ ((t >> 3) & 3)) * 8;
    const unsigned short* gA = X + (size_t)(rowBase + (t >> 2)) * D + swz;
    const unsigned short* gB = Y + (size_t)(colBase + (t >> 2)) * D + swz;

    // Read side: swizzle folds to a per-lane constant.
    const int cread = ((lane >> 4) ^ ((lane >> 1) & 3)) * 8;
    const int aoff = (lane & 15) * 32 + cread;                    // + buf + h*2048 + m*512
    const int boff = 4096 + (w * 64 + (lane & 15)) * 32 + cread;  // + buf + n*512

    f32x4 acc[8][4] = {};

#define STAGE_A(BUF, KT) do { \
    _Pragma("unroll") \
    for (int L = 0; L < 2; ++L) \
        __builtin_amdgcn_global_load_lds( \
            (const __attribute__((address_space(1))) void*)(gA + (size_t)L * 64 * D + (KT) * 32), \
            (__attribute__((address_space(3))) void*)(lds + (BUF) * 12288 + t * 8 + L * 2048), 16, 0, 0); \
} while (0)

#define STAGE_B(BUF, KT) do { \
    _Pragma("unroll") \
    for (int L = 0; L < 4; ++L) \
        __builtin_amdgcn_global_load_lds( \
            (const __attribute__((address_space(1))) void*)(gB + (size_t)L * 64 * D + (KT) * 32), \
            (__attribute__((address_space(3))) void*)(lds + (BUF) * 12288 + 4096 + t * 8 + L * 2048), 16, 0, 0); \
} while (0)

    // Prologue: kt0 + kt1 staged (12 loads); vmcnt(6) -> kt0 landed.
    STAGE_A(0, 0); STAGE_B(0, 0);
    STAGE_A(1, 1); STAGE_B(1, 1);
    asm volatile("s_waitcnt vmcnt(6)" ::: "memory");
    __builtin_amdgcn_s_barrier();

    // 16 K-tiles, buffer = kt%3, ONE merged phase per kt.
#pragma unroll
    for (int kt = 0; kt < 16; ++kt) {
        bf16x8 _a[2][4], _b[4];
        #pragma unroll
        for (int n = 0; n < 4; ++n)
            _b[n] = *(const bf16x8*)(lds + (kt % 3) * 12288 + boff + n * 512);
        #pragma unroll
        for (int h = 0; h < 2; ++h)
            #pragma unroll
            for (int m = 0; m < 4; ++m)
                _a[h][m] = *(const bf16x8*)(lds + (kt % 3) * 12288 + aoff + h * 2048 + m * 512);
        if (kt + 2 < 16) {
            STAGE_A(((kt + 2) % 3), kt + 2);
            STAGE_B(((kt + 2) % 3), kt + 2);
        }
        __builtin_amdgcn_s_setprio(1);
        #pragma unroll
        for (int h = 0; h < 2; ++h)
            #pragma unroll
            for (int m = 0; m < 4; ++m)
                #pragma unroll
                for (int n = 0; n < 4; ++n)
                    acc[h * 4 + m][n] = __builtin_amdgcn_mfma_f32_16x16x32_bf16(
                        _a[h][m], _b[n], acc[h * 4 + m][n], 0, 0, 0);
        __builtin_amdgcn_s_setprio(0);
        __builtin_amdgcn_sched_barrier(0);
        if (kt < 14)       { asm volatile("s_waitcnt vmcnt(6)" ::: "memory"); }
        else if (kt == 14) { asm volatile("s_waitcnt vmcnt(0)" ::: "memory"); }
        if (kt < 15) __builtin_amdgcn_s_barrier();
    }
#undef STAGE_A
#undef STAGE_B

    // Epilogue: C/D layout col = lane&15, row = (lane>>4)*4 + reg.
    // Non-temporal: write-once stream must not evict L2-resident panels.
    const int col0 = colBase + w * 64 + (lane & 15);
    const int row0 = rowBase + ((lane >> 4) << 2);
    #pragma unroll
    for (int mi = 0; mi < 8; ++mi) {
        const int rbase = row0 + (mi >> 2) * 64 + (mi & 3) * 16;
        #pragma unroll
        for (int q = 0; q < 4; ++q) {
            const int grow = rbase + q;
            const float xn = x2[grow];
            float* orow = out + (size_t)grow * NT;
            #pragma unroll
            for (int n = 0; n < 4; ++n) {
                const int gcol = col0 + n * 16;
                float sq = fmaxf(xn + y2[gcol] - 2.0f * acc[mi][n][q], 0.0f);
                __builtin_nontemporal_store(fminf(rsqrtf(sq), 1.0e6f), orow + gcol);
            }
        }
    }
}

extern "C" void kernel_launch(void* const* d_in, const int* in_sizes, int n_in,
                              void* d_out, int out_size, void* d_ws, size_t ws_size,
                              hipStream_t stream)
{
    const float* x = (const float*)d_in[0];
    const float* y = (const float*)d_in[1];
    float* out = (float*)d_out;
    char* ws = (char*)d_ws;

    unsigned short* xb = (unsigned short*)ws;                 // 4 MB
    unsigned short* yb = (unsigned short*)(ws + (4u << 20));  // 8 MB
    float* x2 = (float*)(ws + (12u << 20));                   // 16 KB
    float* y2 = (float*)(ws + (12u << 20) + 4 * NB);          // 32 KB

    prep_kernel<<<(NB + NT) / 4, 256, 0, stream>>>(x, y, xb, yb, x2, y2, out);
    gemm_sim_kernel<<<1024, 256, 0, stream>>>(xb, yb, x2, y2, out + (size_t)NB * D);
}

// Round 15
// 67.027 us; speedup vs baseline: 1.1948x; 1.1742x over previous
//
#include <hip/hip_runtime.h>
#include <hip/hip_bf16.h>
#include <stdint.h>

typedef short bf16x8 __attribute__((ext_vector_type(8)));
typedef float f32x4 __attribute__((ext_vector_type(4)));
typedef float f32x16 __attribute__((ext_vector_type(16)));

#define D  512
#define NB 4096
#define NT 8192

__device__ __forceinline__ unsigned short f2bf(float f) {
    __hip_bfloat16 h = __float2bfloat16(f);
    return *reinterpret_cast<unsigned short*>(&h);
}

// Fused fp32->bf16 convert + row squared-norm for BOTH inputs; x rows also
// write the fp32 passthrough (output 0). One wave per row. HBM-floor bound.
__global__ __launch_bounds__(256) void prep_kernel(
    const float* __restrict__ x, const float* __restrict__ y,
    unsigned short* __restrict__ xb, unsigned short* __restrict__ yb,
    float* __restrict__ x2, float* __restrict__ y2, float* __restrict__ copy)
{
    const int grow = blockIdx.x * 4 + (threadIdx.x >> 6);
    const int lane = threadIdx.x & 63;
    const bool isX = grow < NB;
    const int row  = isX ? grow : grow - NB;
    const float* src = isX ? x : y;
    unsigned short* dst = isX ? xb : yb;
    float* norms = isX ? x2 : y2;

    const float4* rp = reinterpret_cast<const float4*>(src + (size_t)row * D);
    float4 v0 = rp[lane * 2];
    float4 v1 = rp[lane * 2 + 1];
    if (isX) {
        float4* cp = reinterpret_cast<float4*>(copy + (size_t)row * D);
        cp[lane * 2]     = v0;
        cp[lane * 2 + 1] = v1;
    }
    float s = v0.x*v0.x + v0.y*v0.y + v0.z*v0.z + v0.w*v0.w
            + v1.x*v1.x + v1.y*v1.y + v1.z*v1.z + v1.w*v1.w;
    union { unsigned short h[8]; int4 v; } u;
    u.h[0] = f2bf(v0.x); u.h[1] = f2bf(v0.y); u.h[2] = f2bf(v0.z); u.h[3] = f2bf(v0.w);
    u.h[4] = f2bf(v1.x); u.h[5] = f2bf(v1.y); u.h[6] = f2bf(v1.z); u.h[7] = f2bf(v1.w);
    reinterpret_cast<int4*>(dst + (size_t)row * D)[lane] = u.v;
    #pragma unroll
    for (int off = 32; off > 0; off >>= 1) s += __shfl_xor(s, off);
    if (lane == 0) norms[row] = s;
}

// R10 structure (128x256 tile, BK=32, 4 waves 1Mx4N wave-tile 128x64,
// 3 rotating LDS bufs, merged single-phase kt, 1 barrier/kt, counted
// vmcnt(6)) with ONE change: 32x32x16 MFMA instead of 16x16x32.
// Per kt/wave: 16 MFMA (was 32) at the faster 32x32 rate (m119: 2495 vs
// 2176 TF), same 12 ds_read_b128, same staged bytes. Fragments: A/B lane l
// = row/col l&31, k-half l>>5, 8 contiguous k; C/D col=lane&31,
// row=(reg&3)+8*(reg>>2)+4*(lane>>5) [m74/m101].
// LDS (ushort): buf b at b*12288: A 128x32 @+0, B 256x32 @+4096. 72 KiB.
__global__ __launch_bounds__(256, 2) void gemm_sim_kernel(
    const unsigned short* __restrict__ X, const unsigned short* __restrict__ Y,
    const float* __restrict__ x2, const float* __restrict__ y2,
    float* __restrict__ out)
{
    __shared__ alignas(16) unsigned short lds[36864];   // 72 KiB

    const int t    = threadIdx.x;
    const int lane = t & 63;
    const int w    = t >> 6;          // 0..3, wave col (64 cols each)

    // XCD swizzle, L2-fit: each XCD covers 16 rowTiles x 8 colTiles
    // (A 2 MB + B 2 MB = 4 MB = per-XCD L2).
    const int bid = blockIdx.x;
    const int xcd = bid & 7;
    const int idx = bid >> 3;                          // 0..127
    const int rowBase = ((xcd >> 2) * 16 + (idx & 15)) * 128;
    const int colBase = ((xcd & 3) * 8 + (idx >> 4)) * 256;

    // Staging: thread t writes 16 B chunks at LDS ushort off t*8 (+L*2048).
    // Chunk-XOR swizzle (rule #21): stored chunk c' holds global chunk
    // c' ^ ((row>>1)&3); folds to t-only constants for all L.
    const int swz = ((t & 3) ^ ((t >> 3) & 3)) * 8;
    const unsigned short* gA = X + (size_t)(rowBase + (t >> 2)) * D + swz;
    const unsigned short* gB = Y + (size_t)(colBase + (t >> 2)) * D + swz;

    // Fragment-read constants (32x32x16): row/col = lane&31, k-half = lane>>5.
    // Stored chunk c' = g ^ ((row>>1)&3); parity folds to (lane>>1)&3 for
    // every 32-aligned m/n tile and both lane halves.
    const int arow_off = (lane & 31) * 32;                       // + buf + mt*1024 + kpart
    const int brow_off = 4096 + (w * 64 + (lane & 31)) * 32;     // + buf + nt*1024 + kpart
    int kpart[2];
    #pragma unroll
    for (int kh = 0; kh < 2; ++kh)
        kpart[kh] = ((kh * 2 + (lane >> 5)) ^ ((lane >> 1) & 3)) * 8;

    f32x16 acc[4][2] = {};

#define STAGE_A(BUF, KT) do { \
    _Pragma("unroll") \
    for (int L = 0; L < 2; ++L) \
        __builtin_amdgcn_global_load_lds( \
            (const __attribute__((address_space(1))) void*)(gA + (size_t)L * 64 * D + (KT) * 32), \
            (__attribute__((address_space(3))) void*)(lds + (BUF) * 12288 + t * 8 + L * 2048), 16, 0, 0); \
} while (0)

#define STAGE_B(BUF, KT) do { \
    _Pragma("unroll") \
    for (int L = 0; L < 4; ++L) \
        __builtin_amdgcn_global_load_lds( \
            (const __attribute__((address_space(1))) void*)(gB + (size_t)L * 64 * D + (KT) * 32), \
            (__attribute__((address_space(3))) void*)(lds + (BUF) * 12288 + 4096 + t * 8 + L * 2048), 16, 0, 0); \
} while (0)

    // Prologue: kt0 + kt1 staged (12 loads); vmcnt(6) -> kt0 landed.
    STAGE_A(0, 0); STAGE_B(0, 0);
    STAGE_A(1, 1); STAGE_B(1, 1);
    asm volatile("s_waitcnt vmcnt(6)" ::: "memory");
    __builtin_amdgcn_s_barrier();

    // 16 K-tiles, buffer = kt%3, ONE merged phase per kt.
#pragma unroll
    for (int kt = 0; kt < 16; ++kt) {
        const int bufo = (kt % 3) * 12288;
        bf16x8 _a[2][4], _b[2][2];
        #pragma unroll
        for (int kh = 0; kh < 2; ++kh) {
            #pragma unroll
            for (int nt = 0; nt < 2; ++nt)
                _b[kh][nt] = *(const bf16x8*)(lds + bufo + brow_off + nt * 1024 + kpart[kh]);
            #pragma unroll
            for (int mt = 0; mt < 4; ++mt)
                _a[kh][mt] = *(const bf16x8*)(lds + bufo + mt * 1024 + arow_off + kpart[kh]);
        }
        if (kt + 2 < 16) {
            STAGE_A(((kt + 2) % 3), kt + 2);
            STAGE_B(((kt + 2) % 3), kt + 2);
        }
        __builtin_amdgcn_s_setprio(1);
        #pragma unroll
        for (int kh = 0; kh < 2; ++kh)
            #pragma unroll
            for (int mt = 0; mt < 4; ++mt)
                #pragma unroll
                for (int nt = 0; nt < 2; ++nt)
                    acc[mt][nt] = __builtin_amdgcn_mfma_f32_32x32x16_bf16(
                        _a[kh][mt], _b[kh][nt], acc[mt][nt], 0, 0, 0);
        __builtin_amdgcn_s_setprio(0);
        __builtin_amdgcn_sched_barrier(0);
        if (kt < 14)       { asm volatile("s_waitcnt vmcnt(6)" ::: "memory"); }
        else if (kt == 14) { asm volatile("s_waitcnt vmcnt(0)" ::: "memory"); }
        if (kt < 15) __builtin_amdgcn_s_barrier();
    }
#undef STAGE_A
#undef STAGE_B

    // Epilogue: 32x32 C/D layout col = lane&31, row = (p&3)+8*(p>>2)+4*(lane>>5).
    const int colW = colBase + w * 64 + (lane & 31);
    const int rowW = rowBase + 4 * (lane >> 5);
    #pragma unroll
    for (int mt = 0; mt < 4; ++mt) {
        #pragma unroll
        for (int p = 0; p < 16; ++p) {
            const int grow = rowW + mt * 32 + (p & 3) + 8 * (p >> 2);
            const float xn = x2[grow];
            float* orow = out + (size_t)grow * NT;
            #pragma unroll
            for (int nt = 0; nt < 2; ++nt) {
                const int gcol = colW + nt * 32;
                float sq = fmaxf(xn + y2[gcol] - 2.0f * acc[mt][nt][p], 0.0f);
                orow[gcol] = fminf(rsqrtf(sq), 1.0e6f);  // rsqrt(0)=inf -> clipped
            }
        }
    }
}

extern "C" void kernel_launch(void* const* d_in, const int* in_sizes, int n_in,
                              void* d_out, int out_size, void* d_ws, size_t ws_size,
                              hipStream_t stream)
{
    const float* x = (const float*)d_in[0];
    const float* y = (const float*)d_in[1];
    float* out = (float*)d_out;
    char* ws = (char*)d_ws;

    unsigned short* xb = (unsigned short*)ws;                 // 4 MB
    unsigned short* yb = (unsigned short*)(ws + (4u << 20));  // 8 MB
    float* x2 = (float*)(ws + (12u << 20));                   // 16 KB
    float* y2 = (float*)(ws + (12u << 20) + 4 * NB);          // 32 KB

    prep_kernel<<<(NB + NT) / 4, 256, 0, stream>>>(x, y, xb, yb, x2, y2, out);
    gemm_sim_kernel<<<1024, 256, 0, stream>>>(xb, yb, x2, y2, out + (size_t)NB * D);
}

// Round 16
// 59.024 us; speedup vs baseline: 1.3568x; 1.1356x over previous
//
#include <hip/hip_runtime.h>
#include <hip/hip_bf16.h>
#include <stdint.h>

typedef short bf16x8 __attribute__((ext_vector_type(8)));
typedef float f32x4 __attribute__((ext_vector_type(4)));

#define D  512
#define NB 4096
#define NT 8192

__device__ __forceinline__ unsigned short f2bf(float f) {
    __hip_bfloat16 h = __float2bfloat16(f);
    return *reinterpret_cast<unsigned short*>(&h);
}

// Fused fp32->bf16 convert + row squared-norm for BOTH inputs; x rows also
// write the fp32 passthrough (output 0). One wave per row. HBM-floor bound.
__global__ __launch_bounds__(256) void prep_kernel(
    const float* __restrict__ x, const float* __restrict__ y,
    unsigned short* __restrict__ xb, unsigned short* __restrict__ yb,
    float* __restrict__ x2, float* __restrict__ y2, float* __restrict__ copy)
{
    const int grow = blockIdx.x * 4 + (threadIdx.x >> 6);
    const int lane = threadIdx.x & 63;
    const bool isX = grow < NB;
    const int row  = isX ? grow : grow - NB;
    const float* src = isX ? x : y;
    unsigned short* dst = isX ? xb : yb;
    float* norms = isX ? x2 : y2;

    const float4* rp = reinterpret_cast<const float4*>(src + (size_t)row * D);
    float4 v0 = rp[lane * 2];
    float4 v1 = rp[lane * 2 + 1];
    if (isX) {
        float4* cp = reinterpret_cast<float4*>(copy + (size_t)row * D);
        cp[lane * 2]     = v0;
        cp[lane * 2 + 1] = v1;
    }
    float s = v0.x*v0.x + v0.y*v0.y + v0.z*v0.z + v0.w*v0.w
            + v1.x*v1.x + v1.y*v1.y + v1.z*v1.z + v1.w*v1.w;
    union { unsigned short h[8]; int4 v; } u;
    u.h[0] = f2bf(v0.x); u.h[1] = f2bf(v0.y); u.h[2] = f2bf(v0.z); u.h[3] = f2bf(v0.w);
    u.h[4] = f2bf(v1.x); u.h[5] = f2bf(v1.y); u.h[6] = f2bf(v1.z); u.h[7] = f2bf(v1.w);
    reinterpret_cast<int4*>(dst + (size_t)row * D)[lane] = u.v;
    #pragma unroll
    for (int off = 32; off > 0; off >>= 1) s += __shfl_xor(s, off);
    if (lane == 0) norms[row] = s;
}

// m97-faithful port: 128x128 tile, BK=64, 4 waves (2x2, wave-tile 64x64,
// acc=64 VGPR), SINGLE 32 KiB LDS buffer, drain-per-K-step schedule
// (stage -> vmcnt(0) -> barrier -> compute -> lgkm(0) -> barrier).
// The drain stall is hidden by 3 blocks/CU co-residency (m114 mechanism;
// m97 measured 874-912 TF in exactly this config), which also gives
// fine-grained 3-way-staggered store bursts across 8 block generations.
// BK=64 rows are 128 B -> XOR swizzle chunk^=(row&7) (source: t-only
// constant; read: per-lane constant; every 16-lane phase = 2 lanes/bank
// group = free per m136).
// LDS (ushort): A[128][64] @0 (16 KB), B[128][64] @8192 (16 KB).
__global__ __launch_bounds__(256, 3) void gemm_sim_kernel(
    const unsigned short* __restrict__ X, const unsigned short* __restrict__ Y,
    const float* __restrict__ x2, const float* __restrict__ y2,
    float* __restrict__ out)
{
    __shared__ alignas(16) unsigned short lds[16384];   // 32 KiB

    const int t    = threadIdx.x;
    const int lane = t & 63;
    const int w    = t >> 6;          // 0..3
    const int wr   = w >> 1;          // 0..1 (row half, 64 rows)
    const int wc   = w & 1;           // 0..1 (col half, 64 cols)

    // 2048 blocks; per XCD 16 rowTiles x 16 colTiles (A 2MB + B 2MB L2-fit).
    const int bid = blockIdx.x;
    const int xcd = bid & 7;
    const int idx = bid >> 3;                          // 0..255
    const int rowBase = ((xcd & 1) * 16 + (idx & 15)) * 128;
    const int colBase = ((xcd >> 1) * 16 + (idx >> 4)) * 128;

    // Staging: thread t writes 16 B (8 ushorts) at LDS off t*8 (+L*2048),
    // i.e. row (t>>3)+L*32, stored chunk t&7. Source pre-swizzle (rule #21):
    // global chunk g = (t&7) ^ ((t>>3)&7)  (row&7 invariant under +32).
    const int g = ((t & 7) ^ ((t >> 3) & 7)) * 8;
    const unsigned short* gA = X + (size_t)(rowBase + (t >> 3)) * D + g;
    const unsigned short* gB = Y + (size_t)(colBase + (t >> 3)) * D + g;

    // Read-side swizzled chunk (per kk half): sc = (kk*4 + (lane>>4)) ^ (lane&7).
    int sc[2];
    #pragma unroll
    for (int kk = 0; kk < 2; ++kk)
        sc[kk] = (((kk << 2) | (lane >> 4)) ^ (lane & 7)) * 8;
    const int arow = (wr * 64 + (lane & 15)) * 64;          // + m*16*64 + sc
    const int brow = 8192 + (wc * 64 + (lane & 15)) * 64;   // + n*16*64 + sc

    f32x4 acc[4][4] = {};

#define STAGE(KT) do { \
    _Pragma("unroll") \
    for (int L = 0; L < 4; ++L) { \
        __builtin_amdgcn_global_load_lds( \
            (const __attribute__((address_space(1))) void*)(gA + (size_t)L * 32 * D + (KT) * 64), \
            (__attribute__((address_space(3))) void*)(lds + t * 8 + L * 2048), 16, 0, 0); \
        __builtin_amdgcn_global_load_lds( \
            (const __attribute__((address_space(1))) void*)(gB + (size_t)L * 32 * D + (KT) * 64), \
            (__attribute__((address_space(3))) void*)(lds + 8192 + t * 8 + L * 2048), 16, 0, 0); \
    } \
} while (0)

    // 8 K-steps (K=512 / BK=64), single-buffer drain schedule.
#pragma unroll
    for (int kt = 0; kt < 8; ++kt) {
        STAGE(kt);
        asm volatile("s_waitcnt vmcnt(0)" ::: "memory");
        __builtin_amdgcn_s_barrier();
        #pragma unroll
        for (int kk = 0; kk < 2; ++kk) {
            bf16x8 a[4], b[4];
            #pragma unroll
            for (int m = 0; m < 4; ++m)
                a[m] = *(const bf16x8*)(lds + arow + m * 1024 + sc[kk]);
            #pragma unroll
            for (int n = 0; n < 4; ++n)
                b[n] = *(const bf16x8*)(lds + brow + n * 1024 + sc[kk]);
            __builtin_amdgcn_s_setprio(1);
            #pragma unroll
            for (int m = 0; m < 4; ++m)
                #pragma unroll
                for (int n = 0; n < 4; ++n)
                    acc[m][n] = __builtin_amdgcn_mfma_f32_16x16x32_bf16(
                        a[m], b[n], acc[m][n], 0, 0, 0);
            __builtin_amdgcn_s_setprio(0);
        }
        asm volatile("s_waitcnt lgkmcnt(0)" ::: "memory");
        if (kt < 7) __builtin_amdgcn_s_barrier();
    }
#undef STAGE

    // Epilogue: C/D layout col = lane&15, row = (lane>>4)*4 + reg.
    const int col0 = colBase + wc * 64 + (lane & 15);
    const int row0 = rowBase + wr * 64 + ((lane >> 4) << 2);
    #pragma unroll
    for (int m = 0; m < 4; ++m) {
        #pragma unroll
        for (int q = 0; q < 4; ++q) {
            const int grow = row0 + m * 16 + q;
            const float xn = x2[grow];
            float* orow = out + (size_t)grow * NT;
            #pragma unroll
            for (int n = 0; n < 4; ++n) {
                const int gcol = col0 + n * 16;
                float sq = fmaxf(xn + y2[gcol] - 2.0f * acc[m][n][q], 0.0f);
                orow[gcol] = fminf(rsqrtf(sq), 1.0e6f);  // rsqrt(0)=inf -> clipped
            }
        }
    }
}

extern "C" void kernel_launch(void* const* d_in, const int* in_sizes, int n_in,
                              void* d_out, int out_size, void* d_ws, size_t ws_size,
                              hipStream_t stream)
{
    const float* x = (const float*)d_in[0];
    const float* y = (const float*)d_in[1];
    float* out = (float*)d_out;
    char* ws = (char*)d_ws;

    unsigned short* xb = (unsigned short*)ws;                 // 4 MB
    unsigned short* yb = (unsigned short*)(ws + (4u << 20));  // 8 MB
    float* x2 = (float*)(ws + (12u << 20));                   // 16 KB
    float* y2 = (float*)(ws + (12u << 20) + 4 * NB);          // 32 KB

    prep_kernel<<<(NB + NT) / 4, 256, 0, stream>>>(x, y, xb, yb, x2, y2, out);
    gemm_sim_kernel<<<2048, 256, 0, stream>>>(xb, yb, x2, y2, out + (size_t)NB * D);
}

// Round 17
// 57.953 us; speedup vs baseline: 1.3819x; 1.0185x over previous
//
#include <hip/hip_runtime.h>
#include <hip/hip_bf16.h>
#include <stdint.h>

typedef short bf16x8 __attribute__((ext_vector_type(8)));
typedef float f32x4 __attribute__((ext_vector_type(4)));

#define D  512
#define NB 4096
#define NT 8192

__device__ __forceinline__ unsigned short f2bf(float f) {
    __hip_bfloat16 h = __float2bfloat16(f);
    return *reinterpret_cast<unsigned short*>(&h);
}

// Fused fp32->bf16 convert + row squared-norm for BOTH inputs; x rows also
// write the fp32 passthrough (output 0). One wave per row. HBM-floor bound.
__global__ __launch_bounds__(256) void prep_kernel(
    const float* __restrict__ x, const float* __restrict__ y,
    unsigned short* __restrict__ xb, unsigned short* __restrict__ yb,
    float* __restrict__ x2, float* __restrict__ y2, float* __restrict__ copy)
{
    const int grow = blockIdx.x * 4 + (threadIdx.x >> 6);
    const int lane = threadIdx.x & 63;
    const bool isX = grow < NB;
    const int row  = isX ? grow : grow - NB;
    const float* src = isX ? x : y;
    unsigned short* dst = isX ? xb : yb;
    float* norms = isX ? x2 : y2;

    const float4* rp = reinterpret_cast<const float4*>(src + (size_t)row * D);
    float4 v0 = rp[lane * 2];
    float4 v1 = rp[lane * 2 + 1];
    if (isX) {
        float4* cp = reinterpret_cast<float4*>(copy + (size_t)row * D);
        cp[lane * 2]     = v0;
        cp[lane * 2 + 1] = v1;
    }
    float s = v0.x*v0.x + v0.y*v0.y + v0.z*v0.z + v0.w*v0.w
            + v1.x*v1.x + v1.y*v1.y + v1.z*v1.z + v1.w*v1.w;
    union { unsigned short h[8]; int4 v; } u;
    u.h[0] = f2bf(v0.x); u.h[1] = f2bf(v0.y); u.h[2] = f2bf(v0.z); u.h[3] = f2bf(v0.w);
    u.h[4] = f2bf(v1.x); u.h[5] = f2bf(v1.y); u.h[6] = f2bf(v1.z); u.h[7] = f2bf(v1.w);
    reinterpret_cast<int4*>(dst + (size_t)row * D)[lane] = u.v;
    #pragma unroll
    for (int off = 32; off > 0; off >>= 1) s += __shfl_xor(s, off);
    if (lane == 0) norms[row] = s;
}

// m97-faithful port (R16, 59.0 µs) with ONE change: __launch_bounds__
// min-waves 3 -> 4, capping VGPR at 128 for 4 blocks/CU co-residency
// (16 waves/CU). Mechanism: R16 proved block-level TLP is what hides the
// drain stall + store bursts (m114); 4 co-residents amortize further and
// give a 4-generation store stagger. LDS 4x32 KiB = 128 KiB fits.
// Everything else byte-identical to R16.
__global__ __launch_bounds__(256, 4) void gemm_sim_kernel(
    const unsigned short* __restrict__ X, const unsigned short* __restrict__ Y,
    const float* __restrict__ x2, const float* __restrict__ y2,
    float* __restrict__ out)
{
    __shared__ alignas(16) unsigned short lds[16384];   // 32 KiB

    const int t    = threadIdx.x;
    const int lane = t & 63;
    const int w    = t >> 6;          // 0..3
    const int wr   = w >> 1;          // 0..1 (row half, 64 rows)
    const int wc   = w & 1;           // 0..1 (col half, 64 cols)

    // 2048 blocks; per XCD 16 rowTiles x 16 colTiles (A 2MB + B 2MB L2-fit).
    const int bid = blockIdx.x;
    const int xcd = bid & 7;
    const int idx = bid >> 3;                          // 0..255
    const int rowBase = ((xcd & 1) * 16 + (idx & 15)) * 128;
    const int colBase = ((xcd >> 1) * 16 + (idx >> 4)) * 128;

    // Staging: thread t writes 16 B (8 ushorts) at LDS off t*8 (+L*2048),
    // i.e. row (t>>3)+L*32, stored chunk t&7. Source pre-swizzle (rule #21):
    // global chunk g = (t&7) ^ ((t>>3)&7)  (row&7 invariant under +32).
    const int g = ((t & 7) ^ ((t >> 3) & 7)) * 8;
    const unsigned short* gA = X + (size_t)(rowBase + (t >> 3)) * D + g;
    const unsigned short* gB = Y + (size_t)(colBase + (t >> 3)) * D + g;

    // Read-side swizzled chunk (per kk half): sc = (kk*4 + (lane>>4)) ^ (lane&7).
    int sc[2];
    #pragma unroll
    for (int kk = 0; kk < 2; ++kk)
        sc[kk] = (((kk << 2) | (lane >> 4)) ^ (lane & 7)) * 8;
    const int arow = (wr * 64 + (lane & 15)) * 64;          // + m*16*64 + sc
    const int brow = 8192 + (wc * 64 + (lane & 15)) * 64;   // + n*16*64 + sc

    f32x4 acc[4][4] = {};

#define STAGE(KT) do { \
    _Pragma("unroll") \
    for (int L = 0; L < 4; ++L) { \
        __builtin_amdgcn_global_load_lds( \
            (const __attribute__((address_space(1))) void*)(gA + (size_t)L * 32 * D + (KT) * 64), \
            (__attribute__((address_space(3))) void*)(lds + t * 8 + L * 2048), 16, 0, 0); \
        __builtin_amdgcn_global_load_lds( \
            (const __attribute__((address_space(1))) void*)(gB + (size_t)L * 32 * D + (KT) * 64), \
            (__attribute__((address_space(3))) void*)(lds + 8192 + t * 8 + L * 2048), 16, 0, 0); \
    } \
} while (0)

    // 8 K-steps (K=512 / BK=64), single-buffer drain schedule.
#pragma unroll
    for (int kt = 0; kt < 8; ++kt) {
        STAGE(kt);
        asm volatile("s_waitcnt vmcnt(0)" ::: "memory");
        __builtin_amdgcn_s_barrier();
        #pragma unroll
        for (int kk = 0; kk < 2; ++kk) {
            bf16x8 a[4], b[4];
            #pragma unroll
            for (int m = 0; m < 4; ++m)
                a[m] = *(const bf16x8*)(lds + arow + m * 1024 + sc[kk]);
            #pragma unroll
            for (int n = 0; n < 4; ++n)
                b[n] = *(const bf16x8*)(lds + brow + n * 1024 + sc[kk]);
            __builtin_amdgcn_s_setprio(1);
            #pragma unroll
            for (int m = 0; m < 4; ++m)
                #pragma unroll
                for (int n = 0; n < 4; ++n)
                    acc[m][n] = __builtin_amdgcn_mfma_f32_16x16x32_bf16(
                        a[m], b[n], acc[m][n], 0, 0, 0);
            __builtin_amdgcn_s_setprio(0);
        }
        asm volatile("s_waitcnt lgkmcnt(0)" ::: "memory");
        if (kt < 7) __builtin_amdgcn_s_barrier();
    }
#undef STAGE

    // Epilogue: C/D layout col = lane&15, row = (lane>>4)*4 + reg.
    const int col0 = colBase + wc * 64 + (lane & 15);
    const int row0 = rowBase + wr * 64 + ((lane >> 4) << 2);
    #pragma unroll
    for (int m = 0; m < 4; ++m) {
        #pragma unroll
        for (int q = 0; q < 4; ++q) {
            const int grow = row0 + m * 16 + q;
            const float xn = x2[grow];
            float* orow = out + (size_t)grow * NT;
            #pragma unroll
            for (int n = 0; n < 4; ++n) {
                const int gcol = col0 + n * 16;
                float sq = fmaxf(xn + y2[gcol] - 2.0f * acc[m][n][q], 0.0f);
                orow[gcol] = fminf(rsqrtf(sq), 1.0e6f);  // rsqrt(0)=inf -> clipped
            }
        }
    }
}

extern "C" void kernel_launch(void* const* d_in, const int* in_sizes, int n_in,
                              void* d_out, int out_size, void* d_ws, size_t ws_size,
                              hipStream_t stream)
{
    const float* x = (const float*)d_in[0];
    const float* y = (const float*)d_in[1];
    float* out = (float*)d_out;
    char* ws = (char*)d_ws;

    unsigned short* xb = (unsigned short*)ws;                 // 4 MB
    unsigned short* yb = (unsigned short*)(ws + (4u << 20));  // 8 MB
    float* x2 = (float*)(ws + (12u << 20));                   // 16 KB
    float* y2 = (float*)(ws + (12u << 20) + 4 * NB);          // 32 KB

    prep_kernel<<<(NB + NT) / 4, 256, 0, stream>>>(x, y, xb, yb, x2, y2, out);
    gemm_sim_kernel<<<2048, 256, 0, stream>>>(xb, yb, x2, y2, out + (size_t)NB * D);
}